// Round 1
// baseline (589.617 us; speedup 1.0000x reference)
//
#include <hip/hip_runtime.h>

// GCN 4-layer forward on MI355X.
// Reference: h' = relu( norm_dst * segsum_{dst}( ((h*norm_src) @ W)[src] ) + b )
// norm_src/dst from clipped out/in degrees of the ORIGINAL graph (computed once).
//
// Structure per launch (all on `stream`, graph-capture safe):
//   memset deg -> deg_kernel (int atomics) -> norm_kernel
//   scan_kernel (1 block: exclusive scan of deg_in -> rowptr + cursor)
//   fill_kernel (CSR col list via atomic cursors)
//   4x { gemm_ns<DO> (x = ns[r]*(h@W), W cols in VGPRs) ;
//        gather<D,RELU> (1 wave/node: acc over in-edges, *nd + b, relu) }

namespace {

constexpr int NN = 50000;      // nodes
constexpr int NE = 600000;     // edges
constexpr int INDIM = 128;

__global__ void deg_kernel(const int* __restrict__ src, const int* __restrict__ dst,
                           int* __restrict__ dego, int* __restrict__ degi) {
  int e = blockIdx.x * blockDim.x + threadIdx.x;
  if (e < NE) {
    atomicAdd(&dego[src[e]], 1);
    atomicAdd(&degi[dst[e]], 1);
  }
}

__global__ void norm_kernel(const int* __restrict__ dego, const int* __restrict__ degi,
                            float* __restrict__ ns, float* __restrict__ nd) {
  int i = blockIdx.x * blockDim.x + threadIdx.x;
  if (i < NN) {
    int a = dego[i]; if (a < 1) a = 1;
    int b = degi[i]; if (b < 1) b = 1;
    ns[i] = 1.0f / sqrtf((float)a);
    nd[i] = 1.0f / sqrtf((float)b);
  }
}

// Single-block exclusive scan of deg_in[NN] -> rowptr[NN+1], cursor[NN].
__global__ __launch_bounds__(1024) void scan_kernel(const int* __restrict__ deg,
                                                    int* __restrict__ rowptr,
                                                    int* __restrict__ cursor) {
  __shared__ int sums[1024];
  const int t = threadIdx.x;
  const int chunk = (NN + 1023) / 1024;  // 49
  const int beg = t * chunk;
  const int end = (beg + chunk < NN) ? (beg + chunk) : NN;
  int s = 0;
  for (int i = beg; i < end; ++i) s += deg[i];
  sums[t] = s;
  __syncthreads();
  // Hillis-Steele inclusive scan
  for (int off = 1; off < 1024; off <<= 1) {
    int v = (t >= off) ? sums[t - off] : 0;
    __syncthreads();
    sums[t] += v;
    __syncthreads();
  }
  int run = sums[t] - s;  // exclusive prefix
  for (int i = beg; i < end; ++i) {
    rowptr[i] = run;
    cursor[i] = run;
    run += deg[i];
  }
  if (t == 1023) rowptr[NN] = run;  // == NE
}

__global__ void fill_kernel(const int* __restrict__ src, const int* __restrict__ dst,
                            int* __restrict__ cursor, int* __restrict__ col) {
  int e = blockIdx.x * blockDim.x + threadIdx.x;
  if (e < NE) {
    int pos = atomicAdd(&cursor[dst[e]], 1);
    col[pos] = src[e];
  }
}

// x[r][j] = ns[r] * sum_k h[r][k] * W[k][j]
// 256 threads: j = tid % DO, k-split s = tid / DO (KS = 256/DO splits of SEG = 128/KS).
// Each thread holds its W column segment in VGPRs; h rows staged in LDS, broadcast reads.
template <int DO>
__global__ __launch_bounds__(256) void gemm_ns(const float* __restrict__ h,
                                               const float* __restrict__ W,
                                               const float* __restrict__ ns,
                                               float* __restrict__ x) {
  constexpr int KS = 256 / DO;    // 2 (DO=128) or 4 (DO=64)
  constexpr int SEG = INDIM / KS; // 64 or 32
  const int tid = threadIdx.x;
  const int j = tid % DO;
  const int s = tid / DO;

  float wreg[SEG];
#pragma unroll
  for (int i = 0; i < SEG; ++i) wreg[i] = W[(s * SEG + i) * DO + j];

  __shared__ __align__(16) float hs[4][INDIM];
  __shared__ float ptile[4][KS][DO];

  const int ngroups = (NN + 3) / 4;
  for (int g = blockIdx.x; g < ngroups; g += gridDim.x) {
    const int row0 = g * 4;
    // stage 4 rows
    for (int i = tid; i < 4 * INDIM; i += 256) {
      int r = i / INDIM, k = i % INDIM;
      int row = row0 + r;
      hs[r][k] = (row < NN) ? h[row * INDIM + k] : 0.0f;
    }
    __syncthreads();

    float acc[4] = {0.f, 0.f, 0.f, 0.f};
#pragma unroll
    for (int i = 0; i < SEG; i += 4) {
#pragma unroll
      for (int r = 0; r < 4; ++r) {
        float4 hv = *reinterpret_cast<const float4*>(&hs[r][s * SEG + i]);
        acc[r] = fmaf(hv.x, wreg[i + 0], acc[r]);
        acc[r] = fmaf(hv.y, wreg[i + 1], acc[r]);
        acc[r] = fmaf(hv.z, wreg[i + 2], acc[r]);
        acc[r] = fmaf(hv.w, wreg[i + 3], acc[r]);
      }
    }
#pragma unroll
    for (int r = 0; r < 4; ++r) ptile[r][s][j] = acc[r];
    __syncthreads();

    // reduce KS partials, scale by ns[row], store
    for (int o = tid; o < 4 * DO; o += 256) {
      int r = o / DO, c = o % DO;
      int row = row0 + r;
      if (row < NN) {
        float v = 0.f;
#pragma unroll
        for (int ss = 0; ss < KS; ++ss) v += ptile[r][ss][c];
        x[row * DO + c] = ns[row] * v;
      }
    }
    // next iteration's stage only touches hs after all threads pass the
    // compute->ptile barrier above; reduce reads ptile only. Safe with 2 barriers.
    __syncthreads();
  }
}

// One wave per node: acc_d = sum over in-edges of x[col][d]; out = acc*nd + b (relu?).
template <int D, bool RELU>
__global__ __launch_bounds__(256) void gather_kernel(const float* __restrict__ x,
                                                     const int* __restrict__ rowptr,
                                                     const int* __restrict__ col,
                                                     const float* __restrict__ nd,
                                                     const float* __restrict__ b,
                                                     float* __restrict__ out) {
  const int wid = (blockIdx.x * blockDim.x + threadIdx.x) >> 6;
  const int lane = threadIdx.x & 63;
  if (wid >= NN) return;
  const int beg = rowptr[wid];
  const int end = rowptr[wid + 1];
  float a0 = 0.f, a1 = 0.f;
  for (int e = beg; e < end; ++e) {
    const float* xr = &x[col[e] * D];
    a0 += xr[lane];
    if (D == 128) a1 += xr[lane + 64];
  }
  const float scale = nd[wid];
  float r0 = fmaf(a0, scale, b[lane]);
  if (RELU) r0 = fmaxf(r0, 0.f);
  out[wid * D + lane] = r0;
  if (D == 128) {
    float r1 = fmaf(a1, scale, b[lane + 64]);
    if (RELU) r1 = fmaxf(r1, 0.f);
    out[wid * D + lane + 64] = r1;
  }
}

}  // namespace

extern "C" void kernel_launch(void* const* d_in, const int* in_sizes, int n_in,
                              void* d_out, int out_size, void* d_ws, size_t ws_size,
                              hipStream_t stream) {
  const float* h0  = (const float*)d_in[0];
  const int*   src = (const int*)d_in[1];
  const int*   dst = (const int*)d_in[2];
  const float* W0 = (const float*)d_in[3];
  const float* b0 = (const float*)d_in[4];
  const float* W1 = (const float*)d_in[5];
  const float* b1 = (const float*)d_in[6];
  const float* W2 = (const float*)d_in[7];
  const float* b2 = (const float*)d_in[8];
  const float* W3 = (const float*)d_in[9];
  const float* b3 = (const float*)d_in[10];
  float* out = (float*)d_out;

  // workspace layout (256B aligned)
  char* w = (char*)d_ws;
  size_t off = 0;
  auto take = [&](size_t bytes) {
    char* p = w + off;
    off = (off + bytes + 255) & ~size_t(255);
    return p;
  };
  int*   deg_out = (int*)take(NN * 4);
  int*   deg_in  = (int*)take(NN * 4);
  float* nsrc    = (float*)take(NN * 4);
  float* ndst    = (float*)take(NN * 4);
  int*   rowptr  = (int*)take((NN + 1) * 4);
  int*   cursor  = (int*)take(NN * 4);
  int*   col     = (int*)take(NE * 4);
  float* xbuf    = (float*)take((size_t)NN * 128 * 4);
  float* hbuf    = (float*)take((size_t)NN * 128 * 4);
  (void)ws_size; (void)in_sizes; (void)n_in; (void)out_size;

  // deg_out and deg_in are adjacent allocations but padded; memset separately.
  hipMemsetAsync(deg_out, 0, NN * 4, stream);
  hipMemsetAsync(deg_in, 0, NN * 4, stream);

  const int EB = (NE + 255) / 256;
  const int NB = (NN + 255) / 256;
  deg_kernel<<<EB, 256, 0, stream>>>(src, dst, deg_out, deg_in);
  norm_kernel<<<NB, 256, 0, stream>>>(deg_out, deg_in, nsrc, ndst);
  scan_kernel<<<1, 1024, 0, stream>>>(deg_in, rowptr, cursor);
  fill_kernel<<<EB, 256, 0, stream>>>(src, dst, cursor, col);

  const int GEMM_BLOCKS = 2048;
  const int GATHER_BLOCKS = (NN * 64 + 255) / 256;

  // layer 0: h0 -> x -> hbuf (relu)
  gemm_ns<128><<<GEMM_BLOCKS, 256, 0, stream>>>(h0, W0, nsrc, xbuf);
  gather_kernel<128, true><<<GATHER_BLOCKS, 256, 0, stream>>>(xbuf, rowptr, col, ndst, b0, hbuf);
  // layer 1
  gemm_ns<128><<<GEMM_BLOCKS, 256, 0, stream>>>(hbuf, W1, nsrc, xbuf);
  gather_kernel<128, true><<<GATHER_BLOCKS, 256, 0, stream>>>(xbuf, rowptr, col, ndst, b1, hbuf);
  // layer 2
  gemm_ns<128><<<GEMM_BLOCKS, 256, 0, stream>>>(hbuf, W2, nsrc, xbuf);
  gather_kernel<128, true><<<GATHER_BLOCKS, 256, 0, stream>>>(xbuf, rowptr, col, ndst, b2, hbuf);
  // layer 3: no relu, D=64, straight to d_out
  gemm_ns<64><<<GEMM_BLOCKS, 256, 0, stream>>>(hbuf, W3, nsrc, xbuf);
  gather_kernel<64, false><<<GATHER_BLOCKS, 256, 0, stream>>>(xbuf, rowptr, col, ndst, b3, out);
}

// Round 2
// 475.966 us; speedup vs baseline: 1.2388x; 1.2388x over previous
//
#include <hip/hip_runtime.h>

// GCN 4-layer forward on MI355X.
// Reference: h' = relu( norm_dst * segsum_{dst}( ((h*norm_src) @ W)[src] ) + b )
//
// Round 2: replaced 110us single-block scan with 3-phase device-wide scan;
// GEMM groups 8 rows/iteration (was 4), float4 staging; merged deg memsets.

namespace {

constexpr int NN = 50000;      // nodes
constexpr int NE = 600000;     // edges
constexpr int INDIM = 128;
constexpr int SCAN_BLK = 256;
constexpr int NBLK = (NN + SCAN_BLK - 1) / SCAN_BLK;  // 196

__global__ void deg_kernel(const int* __restrict__ src, const int* __restrict__ dst,
                           int* __restrict__ dego, int* __restrict__ degi) {
  int e = blockIdx.x * blockDim.x + threadIdx.x;
  if (e < NE) {
    atomicAdd(&dego[src[e]], 1);
    atomicAdd(&degi[dst[e]], 1);
  }
}

__global__ void norm_kernel(const int* __restrict__ dego, const int* __restrict__ degi,
                            float* __restrict__ ns, float* __restrict__ nd) {
  int i = blockIdx.x * blockDim.x + threadIdx.x;
  if (i < NN) {
    int a = dego[i]; if (a < 1) a = 1;
    int b = degi[i]; if (b < 1) b = 1;
    ns[i] = 1.0f / sqrtf((float)a);
    nd[i] = 1.0f / sqrtf((float)b);
  }
}

// --- 3-phase scan of deg_in[NN] -> rowptr[NN+1] (exclusive), cursor = rowptr ---

__global__ __launch_bounds__(SCAN_BLK) void scan_phase1(const int* __restrict__ deg,
                                                        int* __restrict__ bsum) {
  __shared__ int ws[SCAN_BLK / 64];
  int i = blockIdx.x * SCAN_BLK + threadIdx.x;
  int v = (i < NN) ? deg[i] : 0;
#pragma unroll
  for (int off = 32; off; off >>= 1) v += __shfl_down(v, off, 64);
  int lane = threadIdx.x & 63, w = threadIdx.x >> 6;
  if (lane == 0) ws[w] = v;
  __syncthreads();
  if (threadIdx.x == 0) {
    int s = 0;
#pragma unroll
    for (int k = 0; k < SCAN_BLK / 64; ++k) s += ws[k];
    bsum[blockIdx.x] = s;
  }
}

__global__ __launch_bounds__(256) void scan_phase2(const int* __restrict__ bsum,
                                                   int* __restrict__ bpre,
                                                   int* __restrict__ rowptr) {
  __shared__ int s[256];
  int t = threadIdx.x;
  int v = (t < NBLK) ? bsum[t] : 0;
  s[t] = v;
  __syncthreads();
  for (int off = 1; off < 256; off <<= 1) {
    int u = (t >= off) ? s[t - off] : 0;
    __syncthreads();
    s[t] += u;
    __syncthreads();
  }
  if (t < NBLK) bpre[t] = s[t] - v;  // exclusive
  if (t == 255) rowptr[NN] = s[255]; // total == NE
}

__global__ __launch_bounds__(SCAN_BLK) void scan_phase3(const int* __restrict__ deg,
                                                        const int* __restrict__ bpre,
                                                        int* __restrict__ rowptr,
                                                        int* __restrict__ cursor) {
  __shared__ int s[SCAN_BLK];
  int t = threadIdx.x;
  int i = blockIdx.x * SCAN_BLK + t;
  int v = (i < NN) ? deg[i] : 0;
  s[t] = v;
  __syncthreads();
  for (int off = 1; off < SCAN_BLK; off <<= 1) {
    int u = (t >= off) ? s[t - off] : 0;
    __syncthreads();
    s[t] += u;
    __syncthreads();
  }
  if (i < NN) {
    int ex = bpre[blockIdx.x] + s[t] - v;
    rowptr[i] = ex;
    cursor[i] = ex;
  }
}

__global__ void fill_kernel(const int* __restrict__ src, const int* __restrict__ dst,
                            int* __restrict__ cursor, int* __restrict__ col) {
  int e = blockIdx.x * blockDim.x + threadIdx.x;
  if (e < NE) {
    int pos = atomicAdd(&cursor[dst[e]], 1);
    col[pos] = src[e];
  }
}

// x[r][j] = ns[r] * sum_k h[r][k] * W[k][j]
// 256 threads: j = tid % DO, k-split s = tid / DO. W column segments in VGPRs;
// 8 h rows staged in LDS per iteration (50000 % 8 == 0, no row bounds checks).
template <int DO>
__global__ __launch_bounds__(256) void gemm_ns(const float* __restrict__ h,
                                               const float* __restrict__ W,
                                               const float* __restrict__ ns,
                                               float* __restrict__ x) {
  constexpr int KS = 256 / DO;    // 2 (DO=128) or 4 (DO=64)
  constexpr int SEG = INDIM / KS; // 64 or 32
  const int tid = threadIdx.x;
  const int j = tid % DO;
  const int s = tid / DO;

  float wreg[SEG];
#pragma unroll
  for (int i = 0; i < SEG; ++i) wreg[i] = W[(s * SEG + i) * DO + j];

  __shared__ __align__(16) float hs[8][INDIM];
  __shared__ float ptile[8][KS][DO];

  const int ngroups = NN / 8;  // 6250 exact
  for (int g = blockIdx.x; g < ngroups; g += gridDim.x) {
    const int row0 = g * 8;
    // stage 8 rows: 1024 floats = one float4 per thread, coalesced
    reinterpret_cast<float4*>(&hs[0][0])[tid] =
        reinterpret_cast<const float4*>(h + (size_t)row0 * INDIM)[tid];
    __syncthreads();

    float acc[8];
#pragma unroll
    for (int r = 0; r < 8; ++r) acc[r] = 0.f;
#pragma unroll
    for (int i = 0; i < SEG; i += 4) {
#pragma unroll
      for (int r = 0; r < 8; ++r) {
        float4 hv = *reinterpret_cast<const float4*>(&hs[r][s * SEG + i]);
        acc[r] = fmaf(hv.x, wreg[i + 0], acc[r]);
        acc[r] = fmaf(hv.y, wreg[i + 1], acc[r]);
        acc[r] = fmaf(hv.z, wreg[i + 2], acc[r]);
        acc[r] = fmaf(hv.w, wreg[i + 3], acc[r]);
      }
    }
#pragma unroll
    for (int r = 0; r < 8; ++r) ptile[r][s][j] = acc[r];
    __syncthreads();

    // reduce KS partials, scale by ns[row], store
    for (int o = tid; o < 8 * DO; o += 256) {
      int r = o / DO, c = o % DO;
      int row = row0 + r;
      float v = 0.f;
#pragma unroll
      for (int ss = 0; ss < KS; ++ss) v += ptile[r][ss][c];
      x[(size_t)row * DO + c] = ns[row] * v;
    }
    __syncthreads();
  }
}

// One wave per node: acc_d = sum over in-edges of x[col][d]; out = acc*nd + b (relu?).
template <int D, bool RELU>
__global__ __launch_bounds__(256) void gather_kernel(const float* __restrict__ x,
                                                     const int* __restrict__ rowptr,
                                                     const int* __restrict__ col,
                                                     const float* __restrict__ nd,
                                                     const float* __restrict__ b,
                                                     float* __restrict__ out) {
  const int wid = (blockIdx.x * blockDim.x + threadIdx.x) >> 6;
  const int lane = threadIdx.x & 63;
  if (wid >= NN) return;
  const int beg = rowptr[wid];
  const int end = rowptr[wid + 1];
  float a0 = 0.f, a1 = 0.f;
  for (int e = beg; e < end; ++e) {
    const float* xr = &x[(size_t)col[e] * D];
    a0 += xr[lane];
    if (D == 128) a1 += xr[lane + 64];
  }
  const float scale = nd[wid];
  float r0 = fmaf(a0, scale, b[lane]);
  if (RELU) r0 = fmaxf(r0, 0.f);
  out[(size_t)wid * D + lane] = r0;
  if (D == 128) {
    float r1 = fmaf(a1, scale, b[lane + 64]);
    if (RELU) r1 = fmaxf(r1, 0.f);
    out[(size_t)wid * D + lane + 64] = r1;
  }
}

}  // namespace

extern "C" void kernel_launch(void* const* d_in, const int* in_sizes, int n_in,
                              void* d_out, int out_size, void* d_ws, size_t ws_size,
                              hipStream_t stream) {
  const float* h0  = (const float*)d_in[0];
  const int*   src = (const int*)d_in[1];
  const int*   dst = (const int*)d_in[2];
  const float* W0 = (const float*)d_in[3];
  const float* b0 = (const float*)d_in[4];
  const float* W1 = (const float*)d_in[5];
  const float* b1 = (const float*)d_in[6];
  const float* W2 = (const float*)d_in[7];
  const float* b2 = (const float*)d_in[8];
  const float* W3 = (const float*)d_in[9];
  const float* b3 = (const float*)d_in[10];
  float* out = (float*)d_out;

  // workspace layout (256B aligned)
  char* w = (char*)d_ws;
  size_t off = 0;
  auto take = [&](size_t bytes) {
    char* p = w + off;
    off = (off + bytes + 255) & ~size_t(255);
    return p;
  };
  int*   deg_out = (int*)take(NN * 4);   // adjacent: one memset covers both
  int*   deg_in  = (int*)take(NN * 4);
  float* nsrc    = (float*)take(NN * 4);
  float* ndst    = (float*)take(NN * 4);
  int*   rowptr  = (int*)take((NN + 1) * 4);
  int*   cursor  = (int*)take(NN * 4);
  int*   col     = (int*)take(NE * 4);
  int*   bsum    = (int*)take(NBLK * 4);
  int*   bpre    = (int*)take(NBLK * 4);
  float* xbuf    = (float*)take((size_t)NN * 128 * 4);
  float* hbuf    = (float*)take((size_t)NN * 128 * 4);
  (void)ws_size; (void)in_sizes; (void)n_in; (void)out_size;

  // one memset spanning deg_out..deg_in (contiguous, 256B-padded)
  hipMemsetAsync(deg_out, 0, (size_t)((char*)nsrc - (char*)deg_out), stream);

  const int EB = (NE + 255) / 256;
  const int NB = (NN + 255) / 256;
  deg_kernel<<<EB, 256, 0, stream>>>(src, dst, deg_out, deg_in);
  norm_kernel<<<NB, 256, 0, stream>>>(deg_out, deg_in, nsrc, ndst);
  scan_phase1<<<NBLK, SCAN_BLK, 0, stream>>>(deg_in, bsum);
  scan_phase2<<<1, 256, 0, stream>>>(bsum, bpre, rowptr);
  scan_phase3<<<NBLK, SCAN_BLK, 0, stream>>>(deg_in, bpre, rowptr, cursor);
  fill_kernel<<<EB, 256, 0, stream>>>(src, dst, cursor, col);

  const int GEMM_BLOCKS = 2048;
  const int GATHER_BLOCKS = (NN * 64 + 255) / 256;

  // layer 0: h0 -> x -> hbuf (relu)
  gemm_ns<128><<<GEMM_BLOCKS, 256, 0, stream>>>(h0, W0, nsrc, xbuf);
  gather_kernel<128, true><<<GATHER_BLOCKS, 256, 0, stream>>>(xbuf, rowptr, col, ndst, b0, hbuf);
  // layer 1
  gemm_ns<128><<<GEMM_BLOCKS, 256, 0, stream>>>(hbuf, W1, nsrc, xbuf);
  gather_kernel<128, true><<<GATHER_BLOCKS, 256, 0, stream>>>(xbuf, rowptr, col, ndst, b1, hbuf);
  // layer 2
  gemm_ns<128><<<GEMM_BLOCKS, 256, 0, stream>>>(hbuf, W2, nsrc, xbuf);
  gather_kernel<128, true><<<GATHER_BLOCKS, 256, 0, stream>>>(xbuf, rowptr, col, ndst, b2, hbuf);
  // layer 3: no relu, D=64, straight to d_out
  gemm_ns<64><<<GEMM_BLOCKS, 256, 0, stream>>>(hbuf, W3, nsrc, xbuf);
  gather_kernel<64, false><<<GATHER_BLOCKS, 256, 0, stream>>>(xbuf, rowptr, col, ndst, b3, out);
}

// Round 3
// 431.653 us; speedup vs baseline: 1.3660x; 1.1027x over previous
//
#include <hip/hip_runtime.h>

// GCN 4-layer forward on MI355X.
// Reference: h' = relu( norm_dst * segsum_{dst}( ((h*norm_src) @ W)[src] ) + b )
//
// Round 3: gather restructured for MLP — float4 per lane, 2 edges/wave-iter
// (4 for D=64), unroll x2 => 4 edges in flight; shfl_xor slot-combine.
// GEMM: 16 rows/group.

namespace {

constexpr int NN = 50000;      // nodes
constexpr int NE = 600000;     // edges
constexpr int INDIM = 128;
constexpr int SCAN_BLK = 256;
constexpr int NBLK = (NN + SCAN_BLK - 1) / SCAN_BLK;  // 196

__global__ void deg_kernel(const int* __restrict__ src, const int* __restrict__ dst,
                           int* __restrict__ dego, int* __restrict__ degi) {
  int e = blockIdx.x * blockDim.x + threadIdx.x;
  if (e < NE) {
    atomicAdd(&dego[src[e]], 1);
    atomicAdd(&degi[dst[e]], 1);
  }
}

__global__ void norm_kernel(const int* __restrict__ dego, const int* __restrict__ degi,
                            float* __restrict__ ns, float* __restrict__ nd) {
  int i = blockIdx.x * blockDim.x + threadIdx.x;
  if (i < NN) {
    int a = dego[i]; if (a < 1) a = 1;
    int b = degi[i]; if (b < 1) b = 1;
    ns[i] = 1.0f / sqrtf((float)a);
    nd[i] = 1.0f / sqrtf((float)b);
  }
}

// --- 3-phase scan of deg_in[NN] -> rowptr[NN+1] (exclusive), cursor = rowptr ---

__global__ __launch_bounds__(SCAN_BLK) void scan_phase1(const int* __restrict__ deg,
                                                        int* __restrict__ bsum) {
  __shared__ int ws[SCAN_BLK / 64];
  int i = blockIdx.x * SCAN_BLK + threadIdx.x;
  int v = (i < NN) ? deg[i] : 0;
#pragma unroll
  for (int off = 32; off; off >>= 1) v += __shfl_down(v, off, 64);
  int lane = threadIdx.x & 63, w = threadIdx.x >> 6;
  if (lane == 0) ws[w] = v;
  __syncthreads();
  if (threadIdx.x == 0) {
    int s = 0;
#pragma unroll
    for (int k = 0; k < SCAN_BLK / 64; ++k) s += ws[k];
    bsum[blockIdx.x] = s;
  }
}

__global__ __launch_bounds__(256) void scan_phase2(const int* __restrict__ bsum,
                                                   int* __restrict__ bpre,
                                                   int* __restrict__ rowptr) {
  __shared__ int s[256];
  int t = threadIdx.x;
  int v = (t < NBLK) ? bsum[t] : 0;
  s[t] = v;
  __syncthreads();
  for (int off = 1; off < 256; off <<= 1) {
    int u = (t >= off) ? s[t - off] : 0;
    __syncthreads();
    s[t] += u;
    __syncthreads();
  }
  if (t < NBLK) bpre[t] = s[t] - v;  // exclusive
  if (t == 255) rowptr[NN] = s[255]; // total == NE
}

__global__ __launch_bounds__(SCAN_BLK) void scan_phase3(const int* __restrict__ deg,
                                                        const int* __restrict__ bpre,
                                                        int* __restrict__ rowptr,
                                                        int* __restrict__ cursor) {
  __shared__ int s[SCAN_BLK];
  int t = threadIdx.x;
  int i = blockIdx.x * SCAN_BLK + t;
  int v = (i < NN) ? deg[i] : 0;
  s[t] = v;
  __syncthreads();
  for (int off = 1; off < SCAN_BLK; off <<= 1) {
    int u = (t >= off) ? s[t - off] : 0;
    __syncthreads();
    s[t] += u;
    __syncthreads();
  }
  if (i < NN) {
    int ex = bpre[blockIdx.x] + s[t] - v;
    rowptr[i] = ex;
    cursor[i] = ex;
  }
}

__global__ void fill_kernel(const int* __restrict__ src, const int* __restrict__ dst,
                            int* __restrict__ cursor, int* __restrict__ col) {
  int e = blockIdx.x * blockDim.x + threadIdx.x;
  if (e < NE) {
    int pos = atomicAdd(&cursor[dst[e]], 1);
    col[pos] = src[e];
  }
}

// x[r][j] = ns[r] * sum_k h[r][k] * W[k][j]
// 256 threads: j = tid % DO, k-split s = tid / DO. W column segments in VGPRs;
// 16 h rows staged in LDS per iteration (50000 % 16 == 0).
template <int DO>
__global__ __launch_bounds__(256) void gemm_ns(const float* __restrict__ h,
                                               const float* __restrict__ W,
                                               const float* __restrict__ ns,
                                               float* __restrict__ x) {
  constexpr int KS = 256 / DO;    // 2 (DO=128) or 4 (DO=64)
  constexpr int SEG = INDIM / KS; // 64 or 32
  constexpr int RG = 16;          // rows per group
  const int tid = threadIdx.x;
  const int j = tid % DO;
  const int s = tid / DO;

  float wreg[SEG];
#pragma unroll
  for (int i = 0; i < SEG; ++i) wreg[i] = W[(s * SEG + i) * DO + j];

  __shared__ __align__(16) float hs[RG][INDIM];
  __shared__ float ptile[RG][KS][DO];

  const int ngroups = NN / RG;  // 3125 exact
  for (int g = blockIdx.x; g < ngroups; g += gridDim.x) {
    const int row0 = g * RG;
    // stage RG rows: RG*128 floats = RG/4 float4 per thread, coalesced
#pragma unroll
    for (int q = 0; q < RG / 4; ++q)
      reinterpret_cast<float4*>(&hs[0][0])[q * 256 + tid] =
          reinterpret_cast<const float4*>(h + (size_t)row0 * INDIM)[q * 256 + tid];
    __syncthreads();

    float acc[RG];
#pragma unroll
    for (int r = 0; r < RG; ++r) acc[r] = 0.f;
#pragma unroll
    for (int i = 0; i < SEG; i += 4) {
#pragma unroll
      for (int r = 0; r < RG; ++r) {
        float4 hv = *reinterpret_cast<const float4*>(&hs[r][s * SEG + i]);
        acc[r] = fmaf(hv.x, wreg[i + 0], acc[r]);
        acc[r] = fmaf(hv.y, wreg[i + 1], acc[r]);
        acc[r] = fmaf(hv.z, wreg[i + 2], acc[r]);
        acc[r] = fmaf(hv.w, wreg[i + 3], acc[r]);
      }
    }
#pragma unroll
    for (int r = 0; r < RG; ++r) ptile[r][s][j] = acc[r];
    __syncthreads();

    // reduce KS partials, scale by ns[row], store
    for (int o = tid; o < RG * DO; o += 256) {
      int r = o / DO, c = o % DO;
      int row = row0 + r;
      float v = 0.f;
#pragma unroll
      for (int ss = 0; ss < KS; ++ss) v += ptile[r][ss][c];
      x[(size_t)row * DO + c] = ns[row] * v;
    }
    __syncthreads();
  }
}

// One wave per node. Lane layout: sub = lane/LPR edge slot, c4 = (lane%LPR)*4
// column. LPR lanes cover a D-dim row with float4; EPW=64/LPR edges in flight,
// unroll x2 => up to 2*EPW edges outstanding. Slot partials combined by
// shfl_xor; lanes < LPR write the coalesced float4 output with nd/bias/relu.
template <int D, bool RELU>
__global__ __launch_bounds__(256) void gather_kernel(const float* __restrict__ x,
                                                     const int* __restrict__ rowptr,
                                                     const int* __restrict__ col,
                                                     const float* __restrict__ nd,
                                                     const float* __restrict__ b,
                                                     float* __restrict__ out) {
  constexpr int LPR = D / 4;     // 32 (D=128) or 16 (D=64)
  constexpr int EPW = 64 / LPR;  // 2 or 4
  const int wid = (blockIdx.x * blockDim.x + threadIdx.x) >> 6;
  const int lane = threadIdx.x & 63;
  if (wid >= NN) return;
  const int sub = lane / LPR;
  const int c4 = (lane % LPR) * 4;
  const int beg = rowptr[wid];
  const int end = rowptr[wid + 1];

  float ax = 0.f, ay = 0.f, az = 0.f, aw = 0.f;
  int e = beg + sub;
  for (; e + EPW < end; e += 2 * EPW) {
    int c0 = col[e];
    int c1 = col[e + EPW];
    float4 v0 = *reinterpret_cast<const float4*>(&x[(size_t)c0 * D + c4]);
    float4 v1 = *reinterpret_cast<const float4*>(&x[(size_t)c1 * D + c4]);
    ax += v0.x + v1.x;
    ay += v0.y + v1.y;
    az += v0.z + v1.z;
    aw += v0.w + v1.w;
  }
  if (e < end) {
    int c0 = col[e];
    float4 v0 = *reinterpret_cast<const float4*>(&x[(size_t)c0 * D + c4]);
    ax += v0.x; ay += v0.y; az += v0.z; aw += v0.w;
  }

  // combine edge slots (lanes differing in the high bits)
#pragma unroll
  for (int off = LPR; off < 64; off <<= 1) {
    ax += __shfl_xor(ax, off, 64);
    ay += __shfl_xor(ay, off, 64);
    az += __shfl_xor(az, off, 64);
    aw += __shfl_xor(aw, off, 64);
  }

  if (lane < LPR) {
    const float s = nd[wid];
    float4 bb = *reinterpret_cast<const float4*>(&b[c4]);
    float4 r;
    r.x = fmaf(ax, s, bb.x);
    r.y = fmaf(ay, s, bb.y);
    r.z = fmaf(az, s, bb.z);
    r.w = fmaf(aw, s, bb.w);
    if (RELU) {
      r.x = fmaxf(r.x, 0.f);
      r.y = fmaxf(r.y, 0.f);
      r.z = fmaxf(r.z, 0.f);
      r.w = fmaxf(r.w, 0.f);
    }
    *reinterpret_cast<float4*>(&out[(size_t)wid * D + c4]) = r;
  }
}

}  // namespace

extern "C" void kernel_launch(void* const* d_in, const int* in_sizes, int n_in,
                              void* d_out, int out_size, void* d_ws, size_t ws_size,
                              hipStream_t stream) {
  const float* h0  = (const float*)d_in[0];
  const int*   src = (const int*)d_in[1];
  const int*   dst = (const int*)d_in[2];
  const float* W0 = (const float*)d_in[3];
  const float* b0 = (const float*)d_in[4];
  const float* W1 = (const float*)d_in[5];
  const float* b1 = (const float*)d_in[6];
  const float* W2 = (const float*)d_in[7];
  const float* b2 = (const float*)d_in[8];
  const float* W3 = (const float*)d_in[9];
  const float* b3 = (const float*)d_in[10];
  float* out = (float*)d_out;

  // workspace layout (256B aligned)
  char* w = (char*)d_ws;
  size_t off = 0;
  auto take = [&](size_t bytes) {
    char* p = w + off;
    off = (off + bytes + 255) & ~size_t(255);
    return p;
  };
  int*   deg_out = (int*)take(NN * 4);   // adjacent: one memset covers both
  int*   deg_in  = (int*)take(NN * 4);
  float* nsrc    = (float*)take(NN * 4);
  float* ndst    = (float*)take(NN * 4);
  int*   rowptr  = (int*)take((NN + 1) * 4);
  int*   cursor  = (int*)take(NN * 4);
  int*   col     = (int*)take(NE * 4);
  int*   bsum    = (int*)take(NBLK * 4);
  int*   bpre    = (int*)take(NBLK * 4);
  float* xbuf    = (float*)take((size_t)NN * 128 * 4);
  float* hbuf    = (float*)take((size_t)NN * 128 * 4);
  (void)ws_size; (void)in_sizes; (void)n_in; (void)out_size;

  // one memset spanning deg_out..deg_in (contiguous, 256B-padded)
  hipMemsetAsync(deg_out, 0, (size_t)((char*)nsrc - (char*)deg_out), stream);

  const int EB = (NE + 255) / 256;
  const int NB = (NN + 255) / 256;
  deg_kernel<<<EB, 256, 0, stream>>>(src, dst, deg_out, deg_in);
  norm_kernel<<<NB, 256, 0, stream>>>(deg_out, deg_in, nsrc, ndst);
  scan_phase1<<<NBLK, SCAN_BLK, 0, stream>>>(deg_in, bsum);
  scan_phase2<<<1, 256, 0, stream>>>(bsum, bpre, rowptr);
  scan_phase3<<<NBLK, SCAN_BLK, 0, stream>>>(deg_in, bpre, rowptr, cursor);
  fill_kernel<<<EB, 256, 0, stream>>>(src, dst, cursor, col);

  const int GEMM_BLOCKS = 2048;
  const int GATHER_BLOCKS = (NN * 64 + 255) / 256;

  // layer 0: h0 -> x -> hbuf (relu)
  gemm_ns<128><<<GEMM_BLOCKS, 256, 0, stream>>>(h0, W0, nsrc, xbuf);
  gather_kernel<128, true><<<GATHER_BLOCKS, 256, 0, stream>>>(xbuf, rowptr, col, ndst, b0, hbuf);
  // layer 1
  gemm_ns<128><<<GEMM_BLOCKS, 256, 0, stream>>>(hbuf, W1, nsrc, xbuf);
  gather_kernel<128, true><<<GATHER_BLOCKS, 256, 0, stream>>>(xbuf, rowptr, col, ndst, b1, hbuf);
  // layer 2
  gemm_ns<128><<<GEMM_BLOCKS, 256, 0, stream>>>(hbuf, W2, nsrc, xbuf);
  gather_kernel<128, true><<<GATHER_BLOCKS, 256, 0, stream>>>(xbuf, rowptr, col, ndst, b2, hbuf);
  // layer 3: no relu, D=64, straight to d_out
  gemm_ns<64><<<GEMM_BLOCKS, 256, 0, stream>>>(hbuf, W3, nsrc, xbuf);
  gather_kernel<64, false><<<GATHER_BLOCKS, 256, 0, stream>>>(xbuf, rowptr, col, ndst, b3, out);
}

// Round 4
// 424.244 us; speedup vs baseline: 1.3898x; 1.0175x over previous
//
#include <hip/hip_runtime.h>

// GCN 4-layer forward on MI355X.
// Reference: h' = relu( norm_dst * segsum_{dst}( ((h*norm_src) @ W)[src] ) + b )
//
// Round 4: GEMM rewritten — W in VGPRs (2 cols x 32 k per thread), 4-way
// k-split reduced via in-wave shfl_xor butterfly (no ptile LDS, 2 barriers),
// bank-conflict-free s-interleaved k chunks, 8.25KB LDS -> 4 blocks/CU.

namespace {

constexpr int NN = 50000;      // nodes
constexpr int NE = 600000;     // edges
constexpr int INDIM = 128;
constexpr int SCAN_BLK = 256;
constexpr int NBLK = (NN + SCAN_BLK - 1) / SCAN_BLK;  // 196

__global__ void deg_kernel(const int* __restrict__ src, const int* __restrict__ dst,
                           int* __restrict__ dego, int* __restrict__ degi) {
  int e = blockIdx.x * blockDim.x + threadIdx.x;
  if (e < NE) {
    atomicAdd(&dego[src[e]], 1);
    atomicAdd(&degi[dst[e]], 1);
  }
}

__global__ void norm_kernel(const int* __restrict__ dego, const int* __restrict__ degi,
                            float* __restrict__ ns, float* __restrict__ nd) {
  int i = blockIdx.x * blockDim.x + threadIdx.x;
  if (i < NN) {
    int a = dego[i]; if (a < 1) a = 1;
    int b = degi[i]; if (b < 1) b = 1;
    ns[i] = 1.0f / sqrtf((float)a);
    nd[i] = 1.0f / sqrtf((float)b);
  }
}

// --- 3-phase scan of deg_in[NN] -> rowptr[NN+1] (exclusive), cursor = rowptr ---

__global__ __launch_bounds__(SCAN_BLK) void scan_phase1(const int* __restrict__ deg,
                                                        int* __restrict__ bsum) {
  __shared__ int ws[SCAN_BLK / 64];
  int i = blockIdx.x * SCAN_BLK + threadIdx.x;
  int v = (i < NN) ? deg[i] : 0;
#pragma unroll
  for (int off = 32; off; off >>= 1) v += __shfl_down(v, off, 64);
  int lane = threadIdx.x & 63, w = threadIdx.x >> 6;
  if (lane == 0) ws[w] = v;
  __syncthreads();
  if (threadIdx.x == 0) {
    int s = 0;
#pragma unroll
    for (int k = 0; k < SCAN_BLK / 64; ++k) s += ws[k];
    bsum[blockIdx.x] = s;
  }
}

__global__ __launch_bounds__(256) void scan_phase2(const int* __restrict__ bsum,
                                                   int* __restrict__ bpre,
                                                   int* __restrict__ rowptr) {
  __shared__ int s[256];
  int t = threadIdx.x;
  int v = (t < NBLK) ? bsum[t] : 0;
  s[t] = v;
  __syncthreads();
  for (int off = 1; off < 256; off <<= 1) {
    int u = (t >= off) ? s[t - off] : 0;
    __syncthreads();
    s[t] += u;
    __syncthreads();
  }
  if (t < NBLK) bpre[t] = s[t] - v;  // exclusive
  if (t == 255) rowptr[NN] = s[255]; // total == NE
}

__global__ __launch_bounds__(SCAN_BLK) void scan_phase3(const int* __restrict__ deg,
                                                        const int* __restrict__ bpre,
                                                        int* __restrict__ rowptr,
                                                        int* __restrict__ cursor) {
  __shared__ int s[SCAN_BLK];
  int t = threadIdx.x;
  int i = blockIdx.x * SCAN_BLK + t;
  int v = (i < NN) ? deg[i] : 0;
  s[t] = v;
  __syncthreads();
  for (int off = 1; off < SCAN_BLK; off <<= 1) {
    int u = (t >= off) ? s[t - off] : 0;
    __syncthreads();
    s[t] += u;
    __syncthreads();
  }
  if (i < NN) {
    int ex = bpre[blockIdx.x] + s[t] - v;
    rowptr[i] = ex;
    cursor[i] = ex;
  }
}

__global__ void fill_kernel(const int* __restrict__ src, const int* __restrict__ dst,
                            int* __restrict__ cursor, int* __restrict__ col) {
  int e = blockIdx.x * blockDim.x + threadIdx.x;
  if (e < NE) {
    int pos = atomicAdd(&cursor[dst[e]], 1);
    col[pos] = src[e];
  }
}

// x[row][j] = ns[row] * sum_k h[row][k] * W[k][j]     (K = 128 always)
//
// Thread layout (256 threads):
//   DO=128: jg = tid>>2 (64 col-pairs), s = tid&3 (4-way k-split), 16 rows/thread
//   DO=64:  rs = tid>>7 (2 row-halves), jg = (tid>>2)&31, s = tid&3, 8 rows/thread
// Thread's k set: k = i*16 + s*4 + kk (i<8, kk<4) — s-interleaved chunks so the
// 4 s-lanes of a cluster read 16 distinct LDS banks per ds_read_b128 (no
// conflicts). W[k][j0..j0+1] held in 32 float2 VGPRs. k-partials reduced with a
// 2-step shfl_xor butterfly over s; predicated float2 stores (static acc idx).
template <int DO>
__global__ __launch_bounds__(256, 4) void gemm_ns(const float* __restrict__ h,
                                                  const float* __restrict__ W,
                                                  const float* __restrict__ ns,
                                                  float* __restrict__ x) {
  constexpr int RG = 16;                    // rows staged per group (50000%16==0)
  constexpr int RT = (DO == 128) ? 16 : 8;  // rows accumulated per thread
  constexpr int SPT = RT / 4;               // rows stored per thread
  const int tid = threadIdx.x;
  const int s = tid & 3;
  const int jg = (DO == 128) ? (tid >> 2) : ((tid >> 2) & 31);
  const int j0 = jg * 2;
  const int r0t = (DO == 128) ? 0 : (tid >> 7) * 8;

  // W columns j0, j0+1 for this thread's 32 k values
  float2 wk[32];
#pragma unroll
  for (int i = 0; i < 8; ++i)
#pragma unroll
    for (int kk = 0; kk < 4; ++kk) {
      int k = i * 16 + s * 4 + kk;
      wk[i * 4 + kk] = *reinterpret_cast<const float2*>(&W[k * DO + j0]);
    }

  __shared__ __align__(16) float hsf[RG * INDIM];
  __shared__ float nss[RG];

  const int ngroups = NN / RG;  // 3125
  for (int g = blockIdx.x; g < ngroups; g += gridDim.x) {
    const int row0 = g * RG;
    // stage 16 rows (2048 floats) + ns
    {
      const float4* src4 = reinterpret_cast<const float4*>(h + (size_t)row0 * INDIM);
      float4* dst4 = reinterpret_cast<float4*>(hsf);
      dst4[tid] = src4[tid];
      dst4[tid + 256] = src4[tid + 256];
      if (tid < RG) nss[tid] = ns[row0 + tid];
    }
    __syncthreads();

    float acc0[RT], acc1[RT];
#pragma unroll
    for (int r = 0; r < RT; ++r) { acc0[r] = 0.f; acc1[r] = 0.f; }

#pragma unroll
    for (int r = 0; r < RT; ++r) {
      const float* hrow = &hsf[(r0t + r) * INDIM + s * 4];
#pragma unroll
      for (int i = 0; i < 8; ++i) {
        float4 hv = *reinterpret_cast<const float4*>(hrow + i * 16);
        float2 w0 = wk[i * 4 + 0], w1 = wk[i * 4 + 1];
        float2 w2 = wk[i * 4 + 2], w3 = wk[i * 4 + 3];
        acc0[r] = fmaf(hv.x, w0.x, acc0[r]); acc1[r] = fmaf(hv.x, w0.y, acc1[r]);
        acc0[r] = fmaf(hv.y, w1.x, acc0[r]); acc1[r] = fmaf(hv.y, w1.y, acc1[r]);
        acc0[r] = fmaf(hv.z, w2.x, acc0[r]); acc1[r] = fmaf(hv.z, w2.y, acc1[r]);
        acc0[r] = fmaf(hv.w, w3.x, acc0[r]); acc1[r] = fmaf(hv.w, w3.y, acc1[r]);
      }
    }

    // butterfly-reduce the 4 k-partials (lanes differing in bits 0..1)
#pragma unroll
    for (int r = 0; r < RT; ++r) {
      acc0[r] += __shfl_xor(acc0[r], 1, 64);
      acc0[r] += __shfl_xor(acc0[r], 2, 64);
      acc1[r] += __shfl_xor(acc1[r], 1, 64);
      acc1[r] += __shfl_xor(acc1[r], 2, 64);
    }

    // predicated stores: lane s stores rows [s*SPT, (s+1)*SPT) — static indices
#pragma unroll
    for (int r = 0; r < RT; ++r) {
      if ((r / SPT) == s) {
        int row = row0 + r0t + r;
        float sc = nss[r0t + r];
        float2 v;
        v.x = acc0[r] * sc;
        v.y = acc1[r] * sc;
        *reinterpret_cast<float2*>(&x[(size_t)row * DO + j0]) = v;
      }
    }
    __syncthreads();
  }
}

// One wave per node. Lane layout: sub = lane/LPR edge slot, c4 = (lane%LPR)*4
// column. LPR lanes cover a D-dim row with float4; EPW=64/LPR edges in flight,
// unroll x2 => up to 2*EPW edges outstanding. Slot partials combined by
// shfl_xor; lanes < LPR write the coalesced float4 output with nd/bias/relu.
template <int D, bool RELU>
__global__ __launch_bounds__(256) void gather_kernel(const float* __restrict__ x,
                                                     const int* __restrict__ rowptr,
                                                     const int* __restrict__ col,
                                                     const float* __restrict__ nd,
                                                     const float* __restrict__ b,
                                                     float* __restrict__ out) {
  constexpr int LPR = D / 4;     // 32 (D=128) or 16 (D=64)
  constexpr int EPW = 64 / LPR;  // 2 or 4
  const int wid = (blockIdx.x * blockDim.x + threadIdx.x) >> 6;
  const int lane = threadIdx.x & 63;
  if (wid >= NN) return;
  const int sub = lane / LPR;
  const int c4 = (lane % LPR) * 4;
  const int beg = rowptr[wid];
  const int end = rowptr[wid + 1];

  float ax = 0.f, ay = 0.f, az = 0.f, aw = 0.f;
  int e = beg + sub;
  for (; e + EPW < end; e += 2 * EPW) {
    int c0 = col[e];
    int c1 = col[e + EPW];
    float4 v0 = *reinterpret_cast<const float4*>(&x[(size_t)c0 * D + c4]);
    float4 v1 = *reinterpret_cast<const float4*>(&x[(size_t)c1 * D + c4]);
    ax += v0.x + v1.x;
    ay += v0.y + v1.y;
    az += v0.z + v1.z;
    aw += v0.w + v1.w;
  }
  if (e < end) {
    int c0 = col[e];
    float4 v0 = *reinterpret_cast<const float4*>(&x[(size_t)c0 * D + c4]);
    ax += v0.x; ay += v0.y; az += v0.z; aw += v0.w;
  }

  // combine edge slots (lanes differing in the high bits)
#pragma unroll
  for (int off = LPR; off < 64; off <<= 1) {
    ax += __shfl_xor(ax, off, 64);
    ay += __shfl_xor(ay, off, 64);
    az += __shfl_xor(az, off, 64);
    aw += __shfl_xor(aw, off, 64);
  }

  if (lane < LPR) {
    const float s = nd[wid];
    float4 bb = *reinterpret_cast<const float4*>(&b[c4]);
    float4 r;
    r.x = fmaf(ax, s, bb.x);
    r.y = fmaf(ay, s, bb.y);
    r.z = fmaf(az, s, bb.z);
    r.w = fmaf(aw, s, bb.w);
    if (RELU) {
      r.x = fmaxf(r.x, 0.f);
      r.y = fmaxf(r.y, 0.f);
      r.z = fmaxf(r.z, 0.f);
      r.w = fmaxf(r.w, 0.f);
    }
    *reinterpret_cast<float4*>(&out[(size_t)wid * D + c4]) = r;
  }
}

}  // namespace

extern "C" void kernel_launch(void* const* d_in, const int* in_sizes, int n_in,
                              void* d_out, int out_size, void* d_ws, size_t ws_size,
                              hipStream_t stream) {
  const float* h0  = (const float*)d_in[0];
  const int*   src = (const int*)d_in[1];
  const int*   dst = (const int*)d_in[2];
  const float* W0 = (const float*)d_in[3];
  const float* b0 = (const float*)d_in[4];
  const float* W1 = (const float*)d_in[5];
  const float* b1 = (const float*)d_in[6];
  const float* W2 = (const float*)d_in[7];
  const float* b2 = (const float*)d_in[8];
  const float* W3 = (const float*)d_in[9];
  const float* b3 = (const float*)d_in[10];
  float* out = (float*)d_out;

  // workspace layout (256B aligned)
  char* w = (char*)d_ws;
  size_t off = 0;
  auto take = [&](size_t bytes) {
    char* p = w + off;
    off = (off + bytes + 255) & ~size_t(255);
    return p;
  };
  int*   deg_out = (int*)take(NN * 4);   // adjacent: one memset covers both
  int*   deg_in  = (int*)take(NN * 4);
  float* nsrc    = (float*)take(NN * 4);
  float* ndst    = (float*)take(NN * 4);
  int*   rowptr  = (int*)take((NN + 1) * 4);
  int*   cursor  = (int*)take(NN * 4);
  int*   col     = (int*)take(NE * 4);
  int*   bsum    = (int*)take(NBLK * 4);
  int*   bpre    = (int*)take(NBLK * 4);
  float* xbuf    = (float*)take((size_t)NN * 128 * 4);
  float* hbuf    = (float*)take((size_t)NN * 128 * 4);
  (void)ws_size; (void)in_sizes; (void)n_in; (void)out_size;

  // one memset spanning deg_out..deg_in (contiguous, 256B-padded)
  hipMemsetAsync(deg_out, 0, (size_t)((char*)nsrc - (char*)deg_out), stream);

  const int EB = (NE + 255) / 256;
  const int NB = (NN + 255) / 256;
  deg_kernel<<<EB, 256, 0, stream>>>(src, dst, deg_out, deg_in);
  norm_kernel<<<NB, 256, 0, stream>>>(deg_out, deg_in, nsrc, ndst);
  scan_phase1<<<NBLK, SCAN_BLK, 0, stream>>>(deg_in, bsum);
  scan_phase2<<<1, 256, 0, stream>>>(bsum, bpre, rowptr);
  scan_phase3<<<NBLK, SCAN_BLK, 0, stream>>>(deg_in, bpre, rowptr, cursor);
  fill_kernel<<<EB, 256, 0, stream>>>(src, dst, cursor, col);

  const int GEMM_BLOCKS = 1024;  // 4 blocks/CU resident; <=3 groups each, balanced
  const int GATHER_BLOCKS = (NN * 64 + 255) / 256;

  // layer 0: h0 -> x -> hbuf (relu)
  gemm_ns<128><<<GEMM_BLOCKS, 256, 0, stream>>>(h0, W0, nsrc, xbuf);
  gather_kernel<128, true><<<GATHER_BLOCKS, 256, 0, stream>>>(xbuf, rowptr, col, ndst, b0, hbuf);
  // layer 1
  gemm_ns<128><<<GEMM_BLOCKS, 256, 0, stream>>>(hbuf, W1, nsrc, xbuf);
  gather_kernel<128, true><<<GATHER_BLOCKS, 256, 0, stream>>>(xbuf, rowptr, col, ndst, b1, hbuf);
  // layer 2
  gemm_ns<128><<<GEMM_BLOCKS, 256, 0, stream>>>(hbuf, W2, nsrc, xbuf);
  gather_kernel<128, true><<<GATHER_BLOCKS, 256, 0, stream>>>(xbuf, rowptr, col, ndst, b2, hbuf);
  // layer 3: no relu, D=64, straight to d_out
  gemm_ns<64><<<GEMM_BLOCKS, 256, 0, stream>>>(hbuf, W3, nsrc, xbuf);
  gather_kernel<64, false><<<GATHER_BLOCKS, 256, 0, stream>>>(xbuf, rowptr, col, ndst, b3, out);
}